// Round 1
// baseline (1160.707 us; speedup 1.0000x reference)
//
#include <hip/hip_runtime.h>
#include <math.h>

// Problem constants (from reference):
//   T=1000, B=256, F_IN=13 (x3 tensors -> 39 features), H=100, 3H=300, N_CLS=20
#define T_STEPS 1000
#define BATCH   256
#define FIN     13
#define XDIM    39
#define XPAD    40     // pad to multiple of 4 for float4 LDS reads
#define HDIM    100
#define G3      300    // 3*H gate rows, PyTorch order [r, z, n]
#define NCLS    20

// One persistent workgroup per batch element. Thread g (<300) owns gate row g:
// it keeps W_ih[g,:] (39) and W_hh[g,:] (100) in registers for all 1000 steps.
// h ping-pongs in LDS; gates exchanged through LDS; 2 barriers per step.
__launch_bounds__(320, 1)
__global__ void gru_persistent(const float* __restrict__ mfcc0,
                               const float* __restrict__ mfcc1,
                               const float* __restrict__ mfcc2,
                               const float* __restrict__ len0,
                               const float* __restrict__ W_ih,
                               const float* __restrict__ W_hh,
                               const float* __restrict__ b_ih,
                               const float* __restrict__ b_hh,
                               const float* __restrict__ W_out,
                               const float* __restrict__ b_out,
                               float* __restrict__ out)
{
    const int b   = blockIdx.x;    // batch element
    const int tid = threadIdx.x;

    __shared__ float h_lds[2][HDIM];   // hidden state ping-pong
    __shared__ float x_lds[2][XPAD];   // input features ping-pong (padded)
    __shared__ float gates[G3];        // r,z rows: (gi+gh); n rows: gi only
    __shared__ float ghn[HDIM];        // n rows: gh part (needs r* scaling)
    __shared__ float feat[2*HDIM];     // [avg | max] for the output linear

    // ---- load this thread's weight rows into registers (one-time, L2-hit) ----
    float wih[XPAD];
    float whh[HDIM];
    float bi = 0.f, bh = 0.f;
    if (tid < G3) {
        #pragma unroll
        for (int i = 0; i < XDIM; ++i) wih[i] = W_ih[tid * XDIM + i];
        wih[XDIM] = 0.f;  // pad (pairs with x_lds[*][39] == 0)
        #pragma unroll
        for (int k = 0; k < HDIM; ++k) whh[k] = W_hh[tid * HDIM + k];
        bi = b_ih[tid];
        bh = b_hh[tid];
    }

    // ---- per-thread x-prefetch source (threads 0..38) ----
    // x = concat(mfcc0, mfcc1, mfcc2) on feature axis; layout [T, B, 13] each.
    const float* xsrc = mfcc0;
    int xoff = 0;
    if (tid < XDIM) {
        const int f = tid % FIN;
        xsrc = (tid < FIN) ? mfcc0 : (tid < 2 * FIN ? mfcc1 : mfcc2);
        xoff = b * FIN + f;
    }

    // ---- init: h = 0, x(t=0), pads ----
    if (tid < HDIM) h_lds[0][tid] = 0.f;
    if (tid < XDIM) x_lds[0][tid] = xsrc[xoff];            // t = 0
    if (tid == XDIM) { x_lds[0][XDIM] = 0.f; x_lds[1][XDIM] = 0.f; }
    __syncthreads();

    float sum = 0.f;
    float mx  = -INFINITY;

    for (int t = 0; t < T_STEPS; ++t) {
        const int cur = t & 1;
        const int nxt = cur ^ 1;

        // prefetch x(t+1) into a register while we compute (hides HBM latency)
        float xpf = 0.f;
        if (tid < XDIM && (t + 1) < T_STEPS)
            xpf = xsrc[(size_t)(t + 1) * (BATCH * FIN) + xoff];

        // ---- phase A: gate pre-activations (thread g = one gate row) ----
        if (tid < G3) {
            float ai = bi;
            float ah = bh;
            const float4* x4 = (const float4*)x_lds[cur];
            #pragma unroll
            for (int i = 0; i < XPAD / 4; ++i) {   // 10 broadcast ds_read_b128
                const float4 v = x4[i];
                ai = fmaf(wih[4*i+0], v.x, ai);
                ai = fmaf(wih[4*i+1], v.y, ai);
                ai = fmaf(wih[4*i+2], v.z, ai);
                ai = fmaf(wih[4*i+3], v.w, ai);
            }
            const float4* h4 = (const float4*)h_lds[cur];
            #pragma unroll
            for (int k = 0; k < HDIM / 4; ++k) {   // 25 broadcast ds_read_b128
                const float4 v = h4[k];
                ah = fmaf(whh[4*k+0], v.x, ah);
                ah = fmaf(whh[4*k+1], v.y, ah);
                ah = fmaf(whh[4*k+2], v.z, ah);
                ah = fmaf(whh[4*k+3], v.w, ah);
            }
            if (tid < 2 * HDIM) {
                gates[tid] = ai + ah;              // r,z: biases merge
            } else {
                gates[tid]      = ai;              // i_n
                ghn[tid - 2*HDIM] = ah;            // h_n (gets r* scaling)
            }
        }
        if (tid < XDIM) x_lds[nxt][tid] = xpf;     // stage x(t+1)
        __syncthreads();

        // ---- phase B: nonlinearity + state update (thread j = hidden unit) ----
        if (tid < HDIM) {
            const float r  = 1.f / (1.f + expf(-gates[tid]));
            const float z  = 1.f / (1.f + expf(-gates[HDIM + tid]));
            const float n  = tanhf(fmaf(r, ghn[tid], gates[2*HDIM + tid]));
            const float ho = h_lds[cur][tid];
            const float hv = fmaf(z, ho - n, n);   // (1-z)*n + z*h
            h_lds[nxt][tid] = hv;
            sum += hv;
            mx = fmaxf(mx, hv);
        }
        __syncthreads();
    }

    // ---- pooling + output linear ----
    if (tid < HDIM) {
        feat[tid]        = sum / len0[b];
        feat[HDIM + tid] = mx;
    }
    __syncthreads();

    if (tid < NCLS) {
        float acc = b_out[tid];
        #pragma unroll 4
        for (int k = 0; k < 2 * HDIM; ++k)
            acc = fmaf(W_out[tid * 2 * HDIM + k], feat[k], acc);
        out[b * NCLS + tid] = acc;
    }
}

extern "C" void kernel_launch(void* const* d_in, const int* in_sizes, int n_in,
                              void* d_out, int out_size, void* d_ws, size_t ws_size,
                              hipStream_t stream)
{
    const float* mfcc0 = (const float*)d_in[0];
    const float* mfcc1 = (const float*)d_in[1];
    const float* mfcc2 = (const float*)d_in[2];
    const float* len0  = (const float*)d_in[3];
    const float* W_ih  = (const float*)d_in[4];
    const float* W_hh  = (const float*)d_in[5];
    const float* b_ih  = (const float*)d_in[6];
    const float* b_hh  = (const float*)d_in[7];
    const float* W_out = (const float*)d_in[8];
    const float* b_out = (const float*)d_in[9];
    float* out = (float*)d_out;

    gru_persistent<<<BATCH, 320, 0, stream>>>(
        mfcc0, mfcc1, mfcc2, len0, W_ih, W_hh, b_ih, b_hh, W_out, b_out, out);
}

// Round 4
// 1114.831 us; speedup vs baseline: 1.0411x; 1.0411x over previous
//
#include <hip/hip_runtime.h>
#include <math.h>

// T=1000, B=256, F_IN=13 x3 -> 39 features, H=100, 3H=300 (PyTorch gate order r,z,n), 20 classes
#define T_STEPS 1000
#define BATCH   256
#define FIN     13
#define XDIM    39
#define XPAD    40
#define HDIM    100
#define G3      300
#define NCLS    20

__device__ __forceinline__ float fast_sigmoid(float v) {
    return 1.f / (1.f + __expf(-v));
}
__device__ __forceinline__ float fast_tanh(float v) {
    // clamp so __expf never overflows; tanh saturates to +-1 well before 15
    const float c = fminf(fmaxf(v, -15.f), 15.f);
    const float e = __expf(2.f * c);
    return (e - 1.f) / (e + 1.f);
}

// 4 independent accumulator chains per dot product (FMA latency ~4 cyc; a single
// serial chain of 139 FMAs was itself a ~556-cycle floor). Inline function, NOT
// a macro: a macro parameter named `w` collides with the `.w` member token.
__device__ __forceinline__ void fma4(const float4& wv, const float4& xv,
                                     float& a0, float& a1, float& a2, float& a3)
{
    a0 = fmaf(wv.x, xv.x, a0);
    a1 = fmaf(wv.y, xv.y, a1);
    a2 = fmaf(wv.z, xv.z, a2);
    a3 = fmaf(wv.w, xv.w, a3);
}

// One persistent block per batch element (256 blocks ~ 1/CU). Thread g owns gate
// row g; its W_ih row (39+1 pad) and W_hh row (100) live in 35 NAMED float4
// registers (no arrays -> nothing the compiler can demote to scratch).
// h/x ping-pong in LDS (broadcast reads); 2 barriers per step.
__launch_bounds__(320, 1)
__global__ void gru_persistent(const float* __restrict__ mfcc0,
                               const float* __restrict__ mfcc1,
                               const float* __restrict__ mfcc2,
                               const float* __restrict__ len0,
                               const float* __restrict__ W_ih,
                               const float* __restrict__ W_hh,
                               const float* __restrict__ b_ih,
                               const float* __restrict__ b_hh,
                               const float* __restrict__ W_out,
                               const float* __restrict__ b_out,
                               float* __restrict__ out)
{
    const int b   = blockIdx.x;
    const int tid = threadIdx.x;
    const int row = (tid < G3) ? tid : (G3 - 1);   // clamp; stores are guarded

    __shared__ __align__(16) float h_lds[2][HDIM]; // 100 floats = 25 float4
    __shared__ __align__(16) float x_lds[2][XPAD]; // 40 floats
    __shared__ float gates[G3];                    // r,z rows: gi+gh ; n rows: gi
    __shared__ float ghn[HDIM];                    // n rows: gh part (scaled by r)
    __shared__ float feat[2 * HDIM];

    // ---- one-time: weight rows into named registers ----
    const float* wihp = W_ih + row * XDIM;                  // scalar loads (39 stride)
    const float4* whp = (const float4*)(W_hh + row * HDIM); // 400B row stride: 16B aligned

#define LDA(i) make_float4(wihp[4*(i)], wihp[4*(i)+1], wihp[4*(i)+2], wihp[4*(i)+3])
    float4 wA0 = LDA(0), wA1 = LDA(1), wA2 = LDA(2), wA3 = LDA(3), wA4 = LDA(4);
    float4 wA5 = LDA(5), wA6 = LDA(6), wA7 = LDA(7), wA8 = LDA(8);
    float4 wA9 = make_float4(wihp[36], wihp[37], wihp[38], 0.f);  // pad pairs with x_lds[39]==0
#undef LDA
    float4 wB0  = whp[0],  wB1  = whp[1],  wB2  = whp[2],  wB3  = whp[3],  wB4  = whp[4];
    float4 wB5  = whp[5],  wB6  = whp[6],  wB7  = whp[7],  wB8  = whp[8],  wB9  = whp[9];
    float4 wB10 = whp[10], wB11 = whp[11], wB12 = whp[12], wB13 = whp[13], wB14 = whp[14];
    float4 wB15 = whp[15], wB16 = whp[16], wB17 = whp[17], wB18 = whp[18], wB19 = whp[19];
    float4 wB20 = whp[20], wB21 = whp[21], wB22 = whp[22], wB23 = whp[23], wB24 = whp[24];

    const float bi = b_ih[row];
    const float bh = b_hh[row];

    // ---- per-thread x streaming source (threads 0..38) ----
    const float* xsrc = mfcc0;
    int xoff = 0;
    if (tid < XDIM) {
        const int f = tid % FIN;
        xsrc = (tid < FIN) ? mfcc0 : (tid < 2 * FIN ? mfcc1 : mfcc2);
        xoff = b * FIN + f;
    }

    if (tid < HDIM) h_lds[0][tid] = 0.f;
    if (tid < XDIM) x_lds[0][tid] = xsrc[xoff];
    if (tid == XDIM) { x_lds[0][XDIM] = 0.f; x_lds[1][XDIM] = 0.f; }
    __syncthreads();

    float sum = 0.f;
    float mx  = -INFINITY;

    for (int t = 0; t < T_STEPS; ++t) {
        const int cur = t & 1;
        const int nxt = cur ^ 1;

        float xpf = 0.f;   // prefetch x(t+1) during compute
        if (tid < XDIM && (t + 1) < T_STEPS)
            xpf = xsrc[(size_t)(t + 1) * (BATCH * FIN) + xoff];

        // ---- phase A: gate pre-activations (uniform control flow) ----
        const float4* x4 = (const float4*)x_lds[cur];
        const float4* h4 = (const float4*)h_lds[cur];

        float i0 = 0.f, i1 = 0.f, i2 = 0.f, i3 = 0.f;
        float4 vv;
        vv = x4[0]; fma4(wA0, vv, i0, i1, i2, i3);
        vv = x4[1]; fma4(wA1, vv, i0, i1, i2, i3);
        vv = x4[2]; fma4(wA2, vv, i0, i1, i2, i3);
        vv = x4[3]; fma4(wA3, vv, i0, i1, i2, i3);
        vv = x4[4]; fma4(wA4, vv, i0, i1, i2, i3);
        vv = x4[5]; fma4(wA5, vv, i0, i1, i2, i3);
        vv = x4[6]; fma4(wA6, vv, i0, i1, i2, i3);
        vv = x4[7]; fma4(wA7, vv, i0, i1, i2, i3);
        vv = x4[8]; fma4(wA8, vv, i0, i1, i2, i3);
        vv = x4[9]; fma4(wA9, vv, i0, i1, i2, i3);
        const float ai = bi + ((i0 + i1) + (i2 + i3));

        float g0 = 0.f, g1 = 0.f, g2 = 0.f, g3 = 0.f;
        vv = h4[0];  fma4(wB0,  vv, g0, g1, g2, g3);
        vv = h4[1];  fma4(wB1,  vv, g0, g1, g2, g3);
        vv = h4[2];  fma4(wB2,  vv, g0, g1, g2, g3);
        vv = h4[3];  fma4(wB3,  vv, g0, g1, g2, g3);
        vv = h4[4];  fma4(wB4,  vv, g0, g1, g2, g3);
        vv = h4[5];  fma4(wB5,  vv, g0, g1, g2, g3);
        vv = h4[6];  fma4(wB6,  vv, g0, g1, g2, g3);
        vv = h4[7];  fma4(wB7,  vv, g0, g1, g2, g3);
        vv = h4[8];  fma4(wB8,  vv, g0, g1, g2, g3);
        vv = h4[9];  fma4(wB9,  vv, g0, g1, g2, g3);
        vv = h4[10]; fma4(wB10, vv, g0, g1, g2, g3);
        vv = h4[11]; fma4(wB11, vv, g0, g1, g2, g3);
        vv = h4[12]; fma4(wB12, vv, g0, g1, g2, g3);
        vv = h4[13]; fma4(wB13, vv, g0, g1, g2, g3);
        vv = h4[14]; fma4(wB14, vv, g0, g1, g2, g3);
        vv = h4[15]; fma4(wB15, vv, g0, g1, g2, g3);
        vv = h4[16]; fma4(wB16, vv, g0, g1, g2, g3);
        vv = h4[17]; fma4(wB17, vv, g0, g1, g2, g3);
        vv = h4[18]; fma4(wB18, vv, g0, g1, g2, g3);
        vv = h4[19]; fma4(wB19, vv, g0, g1, g2, g3);
        vv = h4[20]; fma4(wB20, vv, g0, g1, g2, g3);
        vv = h4[21]; fma4(wB21, vv, g0, g1, g2, g3);
        vv = h4[22]; fma4(wB22, vv, g0, g1, g2, g3);
        vv = h4[23]; fma4(wB23, vv, g0, g1, g2, g3);
        vv = h4[24]; fma4(wB24, vv, g0, g1, g2, g3);
        const float ah = bh + ((g0 + g1) + (g2 + g3));

        if (tid < 2 * HDIM) {
            gates[tid] = ai + ah;                 // r, z rows
        } else if (tid < G3) {
            gates[tid]        = ai;               // i_n
            ghn[tid - 2*HDIM] = ah;               // h_n
        }
        if (tid < XDIM) x_lds[nxt][tid] = xpf;
        __syncthreads();

        // ---- phase B: nonlinearity + state update ----
        if (tid < HDIM) {
            const float r  = fast_sigmoid(gates[tid]);
            const float z  = fast_sigmoid(gates[HDIM + tid]);
            const float n  = fast_tanh(fmaf(r, ghn[tid], gates[2*HDIM + tid]));
            const float ho = h_lds[cur][tid];
            const float hv = fmaf(z, ho - n, n);  // (1-z)*n + z*h
            h_lds[nxt][tid] = hv;
            sum += hv;
            mx = fmaxf(mx, hv);
        }
        __syncthreads();
    }

    // ---- pooling + output linear ----
    if (tid < HDIM) {
        feat[tid]        = sum / len0[b];
        feat[HDIM + tid] = mx;
    }
    __syncthreads();

    if (tid < NCLS) {
        float acc = b_out[tid];
        #pragma unroll 4
        for (int k = 0; k < 2 * HDIM; ++k)
            acc = fmaf(W_out[tid * 2 * HDIM + k], feat[k], acc);
        out[b * NCLS + tid] = acc;
    }
}

extern "C" void kernel_launch(void* const* d_in, const int* in_sizes, int n_in,
                              void* d_out, int out_size, void* d_ws, size_t ws_size,
                              hipStream_t stream)
{
    const float* mfcc0 = (const float*)d_in[0];
    const float* mfcc1 = (const float*)d_in[1];
    const float* mfcc2 = (const float*)d_in[2];
    const float* len0  = (const float*)d_in[3];
    const float* W_ih  = (const float*)d_in[4];
    const float* W_hh  = (const float*)d_in[5];
    const float* b_ih  = (const float*)d_in[6];
    const float* b_hh  = (const float*)d_in[7];
    const float* W_out = (const float*)d_in[8];
    const float* b_out = (const float*)d_in[9];
    float* out = (float*)d_out;

    gru_persistent<<<BATCH, 320, 0, stream>>>(
        mfcc0, mfcc1, mfcc2, len0, W_ih, W_hh, b_ih, b_hh, W_out, b_out, out);
}